// Round 4
// baseline (574.564 us; speedup 1.0000x reference)
//
#include <hip/hip_runtime.h>
#include <hip/hip_bf16.h>
#include <math.h>

#define B_ 16
#define S_ 4096
#define E_ 1024
#define H_ 512

typedef short bf16x8 __attribute__((ext_vector_type(8)));
typedef unsigned short u16x8 __attribute__((ext_vector_type(8)));
typedef float f32x4 __attribute__((ext_vector_type(4)));

__device__ inline unsigned short f2bf(float x) {
    __hip_bfloat16 h = __float2bfloat16(x);
    return *(unsigned short*)&h;
}
__device__ inline float bf2f(unsigned short u) {
    unsigned int x = ((unsigned int)u) << 16;
    float f;
    __builtin_memcpy(&f, &x, 4);
    return f;
}

// Fused prep:
//  blocks 0..127   : We[k][n] -> WeTc chunked bf16 layout:
//                    WeTc[(k>>5)*16384 + n*32 + (k&31)]  (chunk = 32 k's, contiguous 32KB)
//  blocks 128..143 : dp[b][h] = dec[b,:].Wd[:,h] + bd[h] + be[h]  (bo dropped: softmax-invariant)
__global__ __launch_bounds__(256) void prep_kernel(
    const float* __restrict__ We, const float* __restrict__ dec,
    const float* __restrict__ Wd, const float* __restrict__ bd,
    const float* __restrict__ be, unsigned short* __restrict__ WeTc,
    float* __restrict__ dp) {
    int t = threadIdx.x;
    if (blockIdx.x < 128) {
        __shared__ float sT[64][65];
        int k0 = (blockIdx.x >> 3) * 64;
        int n0 = (blockIdx.x & 7) * 64;
#pragma unroll
        for (int p = 0; p < 16; ++p) {
            int idx = p * 256 + t;
            int k = idx >> 6, n = idx & 63;
            sT[n][k] = We[(size_t)(k0 + k) * H_ + n0 + n];
        }
        __syncthreads();
#pragma unroll
        for (int p = 0; p < 16; ++p) {
            int idx = p * 256 + t;
            int n = idx >> 6, k = idx & 63;
            int kk = k0 + k, nn = n0 + n;
            WeTc[(size_t)(kk >> 5) * 16384 + nn * 32 + (kk & 31)] = f2bf(sT[n][k]);
        }
    } else {
        int b = blockIdx.x - 128;
        __shared__ float sdec[E_];
#pragma unroll
        for (int i = 0; i < 4; ++i) sdec[i * 256 + t] = dec[b * E_ + i * 256 + t];
        __syncthreads();
        float a0 = 0.f, a1 = 0.f;
#pragma unroll 8
        for (int e = 0; e < E_; ++e) {
            float d = sdec[e];
            a0 = fmaf(d, Wd[(size_t)e * H_ + t], a0);
            a1 = fmaf(d, Wd[(size_t)e * H_ + 256 + t], a1);
        }
        dp[b * H_ + t] = a0 + bd[t] + be[t];
        dp[b * H_ + 256 + t] = a1 + bd[256 + t] + be[256 + t];
    }
}

// scores[b][s] = sum_h tanh(enc@We + dp) * Wo
// Block: BM=128 s-rows x full H=512, 512 threads (8 waves, 2m x 4n).
// A (enc, fp32->bf16) and B (WeTc) staged in LDS; next chunk prefetched to regs.
// Also emits bf16 enc copy for the ctx pass.
#define BM 128
#define BK 32
#define LDW 40  // padded row (shorts): 80B stride -> 2-way-only frag-read aliasing
#define NCH (E_ / BK)

template <int WRITE_ENCB>
__global__ __launch_bounds__(512, 2) void scores_mfma_kernel(
    const float* __restrict__ enc, const unsigned short* __restrict__ WeTc,
    const float* __restrict__ Wo, const float* __restrict__ dp,
    float* __restrict__ scores, unsigned short* __restrict__ encB) {
    __shared__ unsigned short sA[BM * LDW];  // 10 KB
    __shared__ unsigned short sB[H_ * LDW];  // 40 KB
    __shared__ float sRed[4][BM];            // 2 KB

    int tid = threadIdx.x;
    int wave = tid >> 6, lane = tid & 63;
    int quad = lane >> 4, l16 = lane & 15;
    int wm = wave & 1, wn = wave >> 1;
    size_t m0 = (size_t)blockIdx.x * BM;
    int b = (int)(m0 >> 12);

    // A staging map: row ar = tid>>2 (0..127), col ac = (tid&3)*8
    int ar = tid >> 2;
    int ac = (tid & 3) * 8;
    const float* encP = enc + (m0 + ar) * E_ + ac;
    unsigned short* sAw = sA + ar * LDW + ac;
    unsigned short* encBP = encB + (m0 + ar) * E_ + ac;
    // B staging map: row n = tid, 32 bf16 (one chunk-row)
    unsigned short* sBw = sB + tid * LDW;

    f32x4 acc[4][8];
#pragma unroll
    for (int i = 0; i < 4; ++i)
#pragma unroll
        for (int j = 0; j < 8; ++j) acc[i][j] = (f32x4)0.f;

    // preload chunk 0
    float4 pa0 = *(const float4*)(encP);
    float4 pa1 = *(const float4*)(encP + 4);
    const u16x8* wp0 = (const u16x8*)(WeTc + (size_t)tid * 32);
    u16x8 pb0 = wp0[0], pb1 = wp0[1], pb2 = wp0[2], pb3 = wp0[3];

    const unsigned short* sAr = sA + (wm * 64 + l16) * LDW + quad * 8;
    const unsigned short* sBr = sB + (wn * 128 + l16) * LDW + quad * 8;

    for (int c = 0; c < NCH; ++c) {
        u16x8 ua;
        ua[0] = f2bf(pa0.x); ua[1] = f2bf(pa0.y);
        ua[2] = f2bf(pa0.z); ua[3] = f2bf(pa0.w);
        ua[4] = f2bf(pa1.x); ua[5] = f2bf(pa1.y);
        ua[6] = f2bf(pa1.z); ua[7] = f2bf(pa1.w);
        __syncthreads();  // prior chunk's frag reads complete
        *(u16x8*)sAw = ua;
        *(u16x8*)(sBw) = pb0;
        *(u16x8*)(sBw + 8) = pb1;
        *(u16x8*)(sBw + 16) = pb2;
        *(u16x8*)(sBw + 24) = pb3;
        if (WRITE_ENCB) *(u16x8*)(encBP + c * BK) = ua;
        __syncthreads();  // staging visible
        if (c + 1 < NCH) {  // prefetch next chunk; overlaps MFMA below
            pa0 = *(const float4*)(encP + (c + 1) * BK);
            pa1 = *(const float4*)(encP + (c + 1) * BK + 4);
            const u16x8* wpn = (const u16x8*)(WeTc + (size_t)(c + 1) * 16384 + (size_t)tid * 32);
            pb0 = wpn[0]; pb1 = wpn[1]; pb2 = wpn[2]; pb3 = wpn[3];
        }
        bf16x8 aR[4];
#pragma unroll
        for (int i = 0; i < 4; ++i)
            aR[i] = *(const bf16x8*)(sAr + i * 16 * LDW);
#pragma unroll
        for (int j = 0; j < 8; ++j) {
            bf16x8 bR = *(const bf16x8*)(sBr + j * 16 * LDW);
#pragma unroll
            for (int i = 0; i < 4; ++i)
                acc[i][j] = __builtin_amdgcn_mfma_f32_16x16x32_bf16(aR[i], bR, acc[i][j], 0, 0, 0);
        }
    }

    // Epilogue: tanh(acc + dp) * Wo, reduce over all 512 h
    float dpv[8], wov[8];
    const float* dpb = dp + b * H_;
#pragma unroll
    for (int j = 0; j < 8; ++j) {
        int h = wn * 128 + j * 16 + l16;
        dpv[j] = dpb[h];
        wov[j] = Wo[h];
    }
#pragma unroll
    for (int i = 0; i < 4; ++i)
#pragma unroll
        for (int r = 0; r < 4; ++r) {
            float s = 0.f;
#pragma unroll
            for (int j = 0; j < 8; ++j) {
                float x = acc[i][j][r] + dpv[j];
                float e = __expf(2.f * x);
                s += (1.f - 2.f / (e + 1.f)) * wov[j];
            }
            s += __shfl_xor(s, 1, 64);
            s += __shfl_xor(s, 2, 64);
            s += __shfl_xor(s, 4, 64);
            s += __shfl_xor(s, 8, 64);
            if (l16 == 0) sRed[wn][wm * 64 + i * 16 + quad * 4 + r] = s;
        }
    __syncthreads();
    if (tid < BM) {
        int s_in = (int)(m0 & (S_ - 1)) + tid;
        scores[(size_t)b * S_ + s_in] =
            sRed[0][tid] + sRed[1][tid] + sRed[2][tid] + sRed[3][tid];
    }
}

// in-place softmax over S=4096 per batch row
__global__ __launch_bounds__(256) void softmax_kernel(float* __restrict__ sc) {
    int b = blockIdx.x;
    float* row = sc + (size_t)b * S_;
    int tid = threadIdx.x;
    float v[16];
    float m = -1e30f;
#pragma unroll
    for (int i = 0; i < 16; ++i) {
        v[i] = row[i * 256 + tid];
        m = fmaxf(m, v[i]);
    }
    for (int off = 32; off; off >>= 1) m = fmaxf(m, __shfl_xor(m, off, 64));
    __shared__ float redm[4];
    __shared__ float reds[4];
    if ((tid & 63) == 0) redm[tid >> 6] = m;
    __syncthreads();
    m = fmaxf(fmaxf(redm[0], redm[1]), fmaxf(redm[2], redm[3]));
    float s = 0.f;
#pragma unroll
    for (int i = 0; i < 16; ++i) {
        v[i] = __expf(v[i] - m);
        s += v[i];
    }
    for (int off = 32; off; off >>= 1) s += __shfl_xor(s, off, 64);
    if ((tid & 63) == 0) reds[tid >> 6] = s;
    __syncthreads();
    s = reds[0] + reds[1] + reds[2] + reds[3];
    float inv = 1.f / s;
#pragma unroll
    for (int i = 0; i < 16; ++i) row[i * 256 + tid] = v[i] * inv;
}

// ctx partials from the bf16 enc copy. Block = (b, 128-s chunk); thread owns
// 8 e-cols (16B loads), half the s-rows. 64 partials per b.
__global__ __launch_bounds__(256) void ctx_partial_bf16(
    const unsigned short* __restrict__ encB, const float* __restrict__ attn,
    float* __restrict__ part) {
    int b = blockIdx.x >> 5;
    int c = blockIdx.x & 31;
    int s0 = c * 128;
    int tid = threadIdx.x;
    __shared__ float w[128];
    if (tid < 128) w[tid] = attn[(size_t)b * S_ + s0 + tid];
    __syncthreads();
    int e8 = (tid & 127) * 8;
    int sh = tid >> 7;
    const unsigned short* base = encB + ((size_t)b * S_ + s0 + sh * 64) * E_ + e8;
    const float* wp = w + sh * 64;
    float acc[8];
#pragma unroll
    for (int t = 0; t < 8; ++t) acc[t] = 0.f;
    for (int s = 0; s < 64; s += 4) {
        u16x8 v0 = *(const u16x8*)(base + (size_t)(s + 0) * E_);
        u16x8 v1 = *(const u16x8*)(base + (size_t)(s + 1) * E_);
        u16x8 v2 = *(const u16x8*)(base + (size_t)(s + 2) * E_);
        u16x8 v3 = *(const u16x8*)(base + (size_t)(s + 3) * E_);
        float w0 = wp[s], w1 = wp[s + 1], w2 = wp[s + 2], w3 = wp[s + 3];
#pragma unroll
        for (int t = 0; t < 8; ++t) {
            acc[t] = fmaf(w0, bf2f(v0[t]), acc[t]);
            acc[t] = fmaf(w1, bf2f(v1[t]), acc[t]);
            acc[t] = fmaf(w2, bf2f(v2[t]), acc[t]);
            acc[t] = fmaf(w3, bf2f(v3[t]), acc[t]);
        }
    }
    float* po = part + ((size_t)(b * 64 + c * 2 + sh)) * E_ + e8;
    *(float4*)(po) = make_float4(acc[0], acc[1], acc[2], acc[3]);
    *(float4*)(po + 4) = make_float4(acc[4], acc[5], acc[6], acc[7]);
}

// fp32 fallback (if workspace too small for encB)
__global__ __launch_bounds__(256) void ctx_partial_f32(
    const float* __restrict__ enc, const float* __restrict__ attn,
    float* __restrict__ part) {
    int b = blockIdx.x >> 5;
    int c = blockIdx.x & 31;
    int s0 = c * 128;
    int tid = threadIdx.x;
    __shared__ float w[128];
    if (tid < 128) w[tid] = attn[(size_t)b * S_ + s0 + tid];
    __syncthreads();
    const float* base = enc + ((size_t)b * S_ + s0) * E_ + tid * 4;
    float4 acc = make_float4(0.f, 0.f, 0.f, 0.f);
    for (int s = 0; s < 128; s += 2) {
        float4 v0 = *(const float4*)(base + (size_t)s * E_);
        float4 v1 = *(const float4*)(base + (size_t)(s + 1) * E_);
        float w0 = w[s], w1 = w[s + 1];
        acc.x = fmaf(w0, v0.x, acc.x); acc.y = fmaf(w0, v0.y, acc.y);
        acc.z = fmaf(w0, v0.z, acc.z); acc.w = fmaf(w0, v0.w, acc.w);
        acc.x = fmaf(w1, v1.x, acc.x); acc.y = fmaf(w1, v1.y, acc.y);
        acc.z = fmaf(w1, v1.z, acc.z); acc.w = fmaf(w1, v1.w, acc.w);
    }
    *(float4*)(part + ((size_t)(b * 32 + c)) * E_ + tid * 4) = acc;
}

__global__ __launch_bounds__(256) void ctx_reduce(const float* __restrict__ part,
                                                  float* __restrict__ out, int nch) {
    int idx = blockIdx.x * 256 + threadIdx.x;  // 16*1024
    int b = idx >> 10;
    int e = idx & 1023;
    const float* p = part + (size_t)b * nch * E_ + e;
    float s0 = 0.f, s1 = 0.f, s2 = 0.f, s3 = 0.f;
    for (int c = 0; c < nch; c += 4) {
        s0 += p[(size_t)(c + 0) * E_];
        s1 += p[(size_t)(c + 1) * E_];
        s2 += p[(size_t)(c + 2) * E_];
        s3 += p[(size_t)(c + 3) * E_];
    }
    out[idx] = (s0 + s1) + (s2 + s3);
}

extern "C" void kernel_launch(void* const* d_in, const int* in_sizes, int n_in,
                              void* d_out, int out_size, void* d_ws, size_t ws_size,
                              hipStream_t stream) {
    const float* enc = (const float*)d_in[0];  // [16,4096,1024]
    const float* dec = (const float*)d_in[1];  // [16,1024]
    const float* We  = (const float*)d_in[2];  // [1024,512]
    const float* be  = (const float*)d_in[3];  // [512]
    const float* Wd  = (const float*)d_in[4];  // [1024,512]
    const float* bd  = (const float*)d_in[5];  // [512]
    const float* Wo  = (const float*)d_in[6];  // [512,1]
    float* out = (float*)d_out;                // [16,1024]

    char* w = (char*)d_ws;
    unsigned short* WeTc = (unsigned short*)w;             // 1 MiB
    float* dp = (float*)(w + (1 << 20));                   // 32 KiB
    float* scores = (float*)(w + (1 << 20) + (32 << 10));  // 256 KiB
    float* part = (float*)(w + (2 << 20));                 // up to 4 MiB
    unsigned short* encB = (unsigned short*)(w + (8 << 20));  // 128 MiB
    const size_t need_bf16 = (size_t)(8 << 20) + (size_t)B_ * S_ * E_ * 2;
    bool use_bf16_ctx = ws_size >= need_bf16;

    prep_kernel<<<144, 256, 0, stream>>>(We, dec, Wd, bd, be, WeTc, dp);
    if (use_bf16_ctx) {
        scores_mfma_kernel<1><<<B_ * S_ / BM, 512, 0, stream>>>(enc, WeTc, Wo, dp, scores, encB);
        softmax_kernel<<<B_, 256, 0, stream>>>(scores);
        ctx_partial_bf16<<<B_ * 32, 256, 0, stream>>>(encB, scores, part);
        ctx_reduce<<<B_ * E_ / 256, 256, 0, stream>>>(part, out, 64);
    } else {
        scores_mfma_kernel<0><<<B_ * S_ / BM, 512, 0, stream>>>(enc, WeTc, Wo, dp, scores, encB);
        softmax_kernel<<<B_, 256, 0, stream>>>(scores);
        ctx_partial_f32<<<B_ * 32, 256, 0, stream>>>(enc, scores, part);
        ctx_reduce<<<B_ * E_ / 256, 256, 0, stream>>>(part, out, 32);
    }
}

// Round 5
// 495.929 us; speedup vs baseline: 1.1586x; 1.1586x over previous
//
#include <hip/hip_runtime.h>
#include <hip/hip_bf16.h>
#include <math.h>

#define B_ 16
#define S_ 4096
#define E_ 1024
#define H_ 512

#define BM 128
#define BN 128
#define BK 64
#define NCHUNK (E_ / BK)  // 16

typedef short bf16x8 __attribute__((ext_vector_type(8)));
typedef unsigned short u16x8 __attribute__((ext_vector_type(8)));
typedef float f32x4 __attribute__((ext_vector_type(4)));

__device__ inline unsigned short f2bf(float x) {
    __hip_bfloat16 h = __float2bfloat16(x);
    return *(unsigned short*)&h;
}
__device__ inline float bf2f(unsigned short u) {
    unsigned int x = ((unsigned int)u) << 16;
    float f;
    __builtin_memcpy(&f, &x, 4);
    return f;
}
__device__ __forceinline__ void gld16(const unsigned short* g, unsigned short* l) {
    __builtin_amdgcn_global_load_lds(
        (const __attribute__((address_space(1))) void*)g,
        (__attribute__((address_space(3))) void*)l, 16, 0, 0);
}

// One launch, three jobs:
//  blocks 0..63    : We -> WeTcB bf16, swizzled-chunk layout:
//                    WeTcB[c*32768 + n*64 + cp*8 + j] = We[k][n],
//                    k = c*64 + ((cp ^ (n&7))*8 + j   (bank-conflict-free frags)
//  blocks 64..191  : dp[b][h] = dec[b,:].Wd[:,h] + bd[h] + be[h] (bo: softmax-inv)
//  blocks 192..    : enc fp32 -> encB bf16 (row-major), 16 elems/thread
__global__ __launch_bounds__(256) void prep_conv_kernel(
    const float* __restrict__ enc, const float* __restrict__ We,
    const float* __restrict__ dec, const float* __restrict__ Wd,
    const float* __restrict__ bd, const float* __restrict__ be,
    unsigned short* __restrict__ WeTcB, float* __restrict__ dp,
    unsigned short* __restrict__ encB) {
    __shared__ float red[4][64];
    int bid = blockIdx.x, t = threadIdx.x;
    if (bid < 64) {
        int c = bid >> 2, n0t = (bid & 3) * 128;
#pragma unroll 4
        for (int it = 0; it < 32; ++it) {
            int o = it * 256 + t;
            int n_rel = o >> 6, within = o & 63;
            int cp = within >> 3, j = within & 7;
            int n = n0t + n_rel;
            int k = c * 64 + ((cp ^ (n & 7)) << 3) + j;
            WeTcB[c * 32768 + n * 64 + within] = f2bf(We[(size_t)k * H_ + n]);
        }
    } else if (bid < 192) {
        int id = bid - 64;
        int b = id >> 3, hc = id & 7;
        int h = hc * 64 + (t & 63);
        int ec = t >> 6;
        const float* dr = dec + b * E_ + ec * 256;
        const float* wp = Wd + (size_t)(ec * 256) * H_ + h;
        float acc = 0.f;
#pragma unroll 8
        for (int e = 0; e < 256; ++e) acc = fmaf(dr[e], wp[(size_t)e * H_], acc);
        red[ec][t & 63] = acc;
        __syncthreads();
        if (t < 64) {
            int hh = hc * 64 + t;
            dp[b * H_ + hh] = red[0][t] + red[1][t] + red[2][t] + red[3][t] + bd[hh] + be[hh];
        }
    } else {
        size_t base = ((size_t)(bid - 192) * 256 + t) * 16;
        const float* ep = enc + base;
        unsigned short* op = encB + base;
        float4 v0 = *(const float4*)(ep);
        float4 v1 = *(const float4*)(ep + 4);
        float4 v2 = *(const float4*)(ep + 8);
        float4 v3 = *(const float4*)(ep + 12);
        u16x8 u0, u1;
        u0[0] = f2bf(v0.x); u0[1] = f2bf(v0.y); u0[2] = f2bf(v0.z); u0[3] = f2bf(v0.w);
        u0[4] = f2bf(v1.x); u0[5] = f2bf(v1.y); u0[6] = f2bf(v1.z); u0[7] = f2bf(v1.w);
        u1[0] = f2bf(v2.x); u1[1] = f2bf(v2.y); u1[2] = f2bf(v2.z); u1[3] = f2bf(v2.w);
        u1[4] = f2bf(v3.x); u1[5] = f2bf(v3.y); u1[6] = f2bf(v3.z); u1[7] = f2bf(v3.w);
        *(u16x8*)(op) = u0;
        *(u16x8*)(op + 8) = u1;
    }
}

// m97-style GEMM: parts[nt][b][s] = sum_{h in nt's 128} tanh(enc@We + dp)*Wo
// 128x128x64 tiles, 4 waves (2m x 2n), acc 4x4 frags = 64 AGPR/lane.
// Staging via global_load_lds(16B); XOR swizzle (phys k-block = logical ^ (row&7))
// realized through per-lane global gather addresses -> conflict-free ds_read_b128.
__global__ __launch_bounds__(256, 3) void scores_gemm_kernel(
    const unsigned short* __restrict__ encB, const unsigned short* __restrict__ WeTcB,
    const float* __restrict__ Wo, const float* __restrict__ dp,
    float* __restrict__ parts) {
    __shared__ unsigned short sA[BM * BK];  // 16 KB
    __shared__ unsigned short sB[BN * BK];  // 16 KB
    __shared__ float sRed[2][BM];

    int tid = threadIdx.x;
    int w = tid >> 6, l = tid & 63;
    int l16 = l & 15, quad = l >> 4;
    int wm = w & 1, wn = w >> 1;
    int nt = blockIdx.x & 3;
    size_t mt = blockIdx.x >> 2;
    size_t m0 = mt * BM;
    int n0 = nt * BN;
    int b = (int)(m0 >> 12);

    // staging lane constants
    int lrow = l >> 3, lcp = l & 7;
    int qa = lcp ^ (lrow & 7);  // logical k-block gathered by this lane
    const unsigned short* gA = encB + (m0 + w * 8 + lrow) * E_ + qa * 8;
    const unsigned short* gB = WeTcB + (size_t)n0 * BK + (w * 8) * BK + l * 8;
    unsigned short* sAb = sA + (w * 8) * BK;
    unsigned short* sBb = sB + (w * 8) * BK;

    f32x4 acc[4][4];
#pragma unroll
    for (int i = 0; i < 4; ++i)
#pragma unroll
        for (int j = 0; j < 4; ++j) acc[i][j] = (f32x4)0.f;

    int arow = (wm * 64 + l16) * BK;
    int brow = (wn * 64 + l16) * BK;
    int sw = l16 & 7;

    for (int c = 0; c < NCHUNK; ++c) {
        __syncthreads();  // prior chunk's frag reads complete
        int k0 = c * BK;
#pragma unroll
        for (int i = 0; i < 4; ++i) {
            gld16(gA + (size_t)i * 32 * E_ + k0, sAb + i * 32 * BK);
            gld16(gB + (size_t)c * (H_ * BK) + i * 32 * BK, sBb + i * 32 * BK);
        }
        __syncthreads();  // copies landed (compiler drains vmcnt before barrier)
#pragma unroll
        for (int half = 0; half < 2; ++half) {
            int koff = (((half * 4 + quad) ^ sw) << 3);
            bf16x8 aR[4], bR[4];
#pragma unroll
            for (int i = 0; i < 4; ++i)
                aR[i] = *(const bf16x8*)(sA + arow + i * 16 * BK + koff);
#pragma unroll
            for (int j = 0; j < 4; ++j)
                bR[j] = *(const bf16x8*)(sB + brow + j * 16 * BK + koff);
#pragma unroll
            for (int i = 0; i < 4; ++i)
#pragma unroll
                for (int j = 0; j < 4; ++j)
                    acc[i][j] = __builtin_amdgcn_mfma_f32_16x16x32_bf16(aR[i], bR[j], acc[i][j], 0, 0, 0);
        }
    }

    // Epilogue: tanh(acc + dp) * Wo, partial reduce over this block's 128 h.
    float dpv[4], wov[4];
    const float* dpb = dp + b * H_;
#pragma unroll
    for (int j = 0; j < 4; ++j) {
        int h = n0 + wn * 64 + j * 16 + l16;
        dpv[j] = dpb[h];
        wov[j] = Wo[h];
    }
#pragma unroll
    for (int i = 0; i < 4; ++i)
#pragma unroll
        for (int r = 0; r < 4; ++r) {
            float s = 0.f;
#pragma unroll
            for (int j = 0; j < 4; ++j) {
                float x = acc[i][j][r] + dpv[j];
                float e = __expf(2.f * x);
                s += (1.f - 2.f / (e + 1.f)) * wov[j];
            }
            s += __shfl_xor(s, 1, 64);
            s += __shfl_xor(s, 2, 64);
            s += __shfl_xor(s, 4, 64);
            s += __shfl_xor(s, 8, 64);
            if (l16 == 0) sRed[wn][wm * 64 + i * 16 + quad * 4 + r] = s;
        }
    __syncthreads();
    if (tid < BM) {
        int s_in = (int)(m0 & (S_ - 1)) + tid;
        parts[(size_t)(nt * B_ + b) * S_ + s_in] = sRed[0][tid] + sRed[1][tid];
    }
}

// softmax over S=4096 per batch row; sums the 4 n-split partials, writes attn
// into parts slab 0. float4 loads for ILP.
__global__ __launch_bounds__(256) void softmax_kernel(float* __restrict__ parts) {
    int b = blockIdx.x, tid = threadIdx.x;
    const float4* p0 = (const float4*)(parts + (size_t)(0 * B_ + b) * S_);
    const float4* p1 = (const float4*)(parts + (size_t)(1 * B_ + b) * S_);
    const float4* p2 = (const float4*)(parts + (size_t)(2 * B_ + b) * S_);
    const float4* p3 = (const float4*)(parts + (size_t)(3 * B_ + b) * S_);
    float4* row = (float4*)(parts + (size_t)b * S_);
    float4 v[4];
    float m = -1e30f;
#pragma unroll
    for (int i = 0; i < 4; ++i) {
        int idx = i * 256 + tid;
        float4 a0 = p0[idx], a1 = p1[idx], a2 = p2[idx], a3 = p3[idx];
        v[i].x = a0.x + a1.x + a2.x + a3.x;
        v[i].y = a0.y + a1.y + a2.y + a3.y;
        v[i].z = a0.z + a1.z + a2.z + a3.z;
        v[i].w = a0.w + a1.w + a2.w + a3.w;
        m = fmaxf(m, fmaxf(fmaxf(v[i].x, v[i].y), fmaxf(v[i].z, v[i].w)));
    }
    for (int off = 32; off; off >>= 1) m = fmaxf(m, __shfl_xor(m, off, 64));
    __shared__ float redm[4];
    __shared__ float reds[4];
    if ((tid & 63) == 0) redm[tid >> 6] = m;
    __syncthreads();
    m = fmaxf(fmaxf(redm[0], redm[1]), fmaxf(redm[2], redm[3]));
    float s = 0.f;
#pragma unroll
    for (int i = 0; i < 4; ++i) {
        v[i].x = __expf(v[i].x - m); v[i].y = __expf(v[i].y - m);
        v[i].z = __expf(v[i].z - m); v[i].w = __expf(v[i].w - m);
        s += (v[i].x + v[i].y) + (v[i].z + v[i].w);
    }
    for (int off = 32; off; off >>= 1) s += __shfl_xor(s, off, 64);
    if ((tid & 63) == 0) reds[tid >> 6] = s;
    __syncthreads();
    s = reds[0] + reds[1] + reds[2] + reds[3];
    float inv = 1.f / s;
#pragma unroll
    for (int i = 0; i < 4; ++i) {
        int idx = i * 256 + tid;
        row[idx] = make_float4(v[i].x * inv, v[i].y * inv, v[i].z * inv, v[i].w * inv);
    }
}

// ctx partials from bf16 enc copy. Block = (b, 128-s chunk); thread: 8 e-cols,
// 64 s-rows, unroll 8 for ILP. 64 partial slabs per b.
__global__ __launch_bounds__(256) void ctx_partial_bf16(
    const unsigned short* __restrict__ encB, const float* __restrict__ attn,
    float* __restrict__ part) {
    int b = blockIdx.x >> 5;
    int c = blockIdx.x & 31;
    int s0 = c * 128;
    int tid = threadIdx.x;
    __shared__ float w[128];
    if (tid < 128) w[tid] = attn[(size_t)b * S_ + s0 + tid];
    __syncthreads();
    int e8 = (tid & 127) * 8;
    int sh = tid >> 7;
    const unsigned short* base = encB + ((size_t)b * S_ + s0 + sh * 64) * E_ + e8;
    const float* wp = w + sh * 64;
    float acc[8];
#pragma unroll
    for (int t = 0; t < 8; ++t) acc[t] = 0.f;
    for (int s = 0; s < 64; s += 8) {
        u16x8 v[8];
#pragma unroll
        for (int u = 0; u < 8; ++u) v[u] = *(const u16x8*)(base + (size_t)(s + u) * E_);
#pragma unroll
        for (int u = 0; u < 8; ++u) {
            float ws = wp[s + u];
#pragma unroll
            for (int t = 0; t < 8; ++t) acc[t] = fmaf(ws, bf2f(v[u][t]), acc[t]);
        }
    }
    float* po = part + ((size_t)(b * 64 + c * 2 + sh)) * E_ + e8;
    *(float4*)(po) = make_float4(acc[0], acc[1], acc[2], acc[3]);
    *(float4*)(po + 4) = make_float4(acc[4], acc[5], acc[6], acc[7]);
}

__global__ __launch_bounds__(256) void ctx_reduce(const float* __restrict__ part,
                                                  float* __restrict__ out, int nch) {
    int idx = blockIdx.x * 256 + threadIdx.x;  // 16*1024
    int b = idx >> 10;
    int e = idx & 1023;
    const float* p = part + (size_t)b * nch * E_ + e;
    float s0 = 0.f, s1 = 0.f, s2 = 0.f, s3 = 0.f;
    for (int c = 0; c < nch; c += 4) {
        s0 += p[(size_t)(c + 0) * E_];
        s1 += p[(size_t)(c + 1) * E_];
        s2 += p[(size_t)(c + 2) * E_];
        s3 += p[(size_t)(c + 3) * E_];
    }
    out[idx] = (s0 + s1) + (s2 + s3);
}

extern "C" void kernel_launch(void* const* d_in, const int* in_sizes, int n_in,
                              void* d_out, int out_size, void* d_ws, size_t ws_size,
                              hipStream_t stream) {
    const float* enc = (const float*)d_in[0];  // [16,4096,1024]
    const float* dec = (const float*)d_in[1];  // [16,1024]
    const float* We  = (const float*)d_in[2];  // [1024,512]
    const float* be  = (const float*)d_in[3];  // [512]
    const float* Wd  = (const float*)d_in[4];  // [1024,512]
    const float* bd  = (const float*)d_in[5];  // [512]
    const float* Wo  = (const float*)d_in[6];  // [512,1]
    float* out = (float*)d_out;                // [16,1024]

    char* wsp = (char*)d_ws;
    unsigned short* WeTcB = (unsigned short*)wsp;              // 1 MiB
    float* dp = (float*)(wsp + (1 << 20));                     // 32 KiB
    float* parts = (float*)(wsp + (1 << 20) + (64 << 10));     // 1 MiB (4 slabs)
    float* part = (float*)(wsp + (4 << 20));                   // 4 MiB
    unsigned short* encB = (unsigned short*)(wsp + (8 << 20)); // 128 MiB
    float* attn = parts;  // softmax writes attn into slab 0

    // 192 prep blocks first (start early), then 16384 conversion blocks
    prep_conv_kernel<<<192 + 16384, 256, 0, stream>>>(enc, We, dec, Wd, bd, be,
                                                      WeTcB, dp, encB);
    scores_gemm_kernel<<<(B_ * S_ / BM) * (H_ / BN), 256, 0, stream>>>(
        encB, WeTcB, Wo, dp, parts);
    softmax_kernel<<<B_, 256, 0, stream>>>(parts);
    ctx_partial_bf16<<<B_ * 32, 256, 0, stream>>>(encB, attn, part);
    ctx_reduce<<<B_ * E_ / 256, 256, 0, stream>>>(part, out, 64);
}

// Round 6
// 485.344 us; speedup vs baseline: 1.1838x; 1.0218x over previous
//
#include <hip/hip_runtime.h>
#include <hip/hip_bf16.h>
#include <math.h>

#define B_ 16
#define S_ 4096
#define E_ 1024
#define H_ 512

#define BM 128
#define BN 128
#define BK 64
#define NCHUNK (E_ / BK)  // 16

typedef short bf16x8 __attribute__((ext_vector_type(8)));
typedef unsigned short u16x8 __attribute__((ext_vector_type(8)));
typedef float f32x4 __attribute__((ext_vector_type(4)));

__device__ inline unsigned short f2bf(float x) {
    __hip_bfloat16 h = __float2bfloat16(x);
    return *(unsigned short*)&h;
}
__device__ inline float bf2f(unsigned short u) {
    unsigned int x = ((unsigned int)u) << 16;
    float f;
    __builtin_memcpy(&f, &x, 4);
    return f;
}
__device__ __forceinline__ void gld16(const unsigned short* g, unsigned short* l) {
    __builtin_amdgcn_global_load_lds(
        (const __attribute__((address_space(1))) void*)g,
        (__attribute__((address_space(3))) void*)l, 16, 0, 0);
}

// One launch, three jobs:
//  blocks 0..63    : We -> WeTcB bf16, swizzled-chunk layout:
//                    WeTcB[c*32768 + n*64 + cp*8 + j] = We[k][n],
//                    k = c*64 + (cp ^ (n&7))*8 + j   (bank-conflict-free frags)
//  blocks 64..191  : dp[b][h] = dec[b,:].Wd[:,h] + bd[h] + be[h] (bo: softmax-inv)
//  blocks 192..    : enc fp32 -> encB bf16 (row-major), 16 elems/thread
__global__ __launch_bounds__(256) void prep_conv_kernel(
    const float* __restrict__ enc, const float* __restrict__ We,
    const float* __restrict__ dec, const float* __restrict__ Wd,
    const float* __restrict__ bd, const float* __restrict__ be,
    unsigned short* __restrict__ WeTcB, float* __restrict__ dp,
    unsigned short* __restrict__ encB) {
    __shared__ float red[4][64];
    int bid = blockIdx.x, t = threadIdx.x;
    if (bid < 64) {
        int c = bid >> 2, n0t = (bid & 3) * 128;
#pragma unroll 4
        for (int it = 0; it < 32; ++it) {
            int o = it * 256 + t;
            int n_rel = o >> 6, within = o & 63;
            int cp = within >> 3, j = within & 7;
            int n = n0t + n_rel;
            int k = c * 64 + ((cp ^ (n & 7)) << 3) + j;
            WeTcB[c * 32768 + n * 64 + within] = f2bf(We[(size_t)k * H_ + n]);
        }
    } else if (bid < 192) {
        int id = bid - 64;
        int b = id >> 3, hc = id & 7;
        int h = hc * 64 + (t & 63);
        int ec = t >> 6;
        const float* dr = dec + b * E_ + ec * 256;
        const float* wp = Wd + (size_t)(ec * 256) * H_ + h;
        float acc = 0.f;
#pragma unroll 8
        for (int e = 0; e < 256; ++e) acc = fmaf(dr[e], wp[(size_t)e * H_], acc);
        red[ec][t & 63] = acc;
        __syncthreads();
        if (t < 64) {
            int hh = hc * 64 + t;
            dp[b * H_ + hh] = red[0][t] + red[1][t] + red[2][t] + red[3][t] + bd[hh] + be[hh];
        }
    } else {
        size_t base = ((size_t)(bid - 192) * 256 + t) * 16;
        const float* ep = enc + base;
        unsigned short* op = encB + base;
        float4 v0 = *(const float4*)(ep);
        float4 v1 = *(const float4*)(ep + 4);
        float4 v2 = *(const float4*)(ep + 8);
        float4 v3 = *(const float4*)(ep + 12);
        u16x8 u0, u1;
        u0[0] = f2bf(v0.x); u0[1] = f2bf(v0.y); u0[2] = f2bf(v0.z); u0[3] = f2bf(v0.w);
        u0[4] = f2bf(v1.x); u0[5] = f2bf(v1.y); u0[6] = f2bf(v1.z); u0[7] = f2bf(v1.w);
        u1[0] = f2bf(v2.x); u1[1] = f2bf(v2.y); u1[2] = f2bf(v2.z); u1[3] = f2bf(v2.w);
        u1[4] = f2bf(v3.x); u1[5] = f2bf(v3.y); u1[6] = f2bf(v3.z); u1[7] = f2bf(v3.w);
        *(u16x8*)(op) = u0;
        *(u16x8*)(op + 8) = u1;
    }
}

// m97-style GEMM: parts[nt][b][s] = sum_{h in nt's 128} tanh(enc@We + dp)*Wo
// 128x128x64 tiles, 4 waves (2m x 2n), acc 4x4 frags = 64 AGPR/lane.
// Staging via global_load_lds(16B); XOR swizzle (phys k-block = logical ^ (row&7))
// realized through per-lane global gather addresses -> conflict-free ds_read_b128.
// Block remap: the 4 nt-siblings of an m-tile land on the same XCD (bid%8
// round-robin heuristic) so the A-tile is fetched from L3 once, then L2-hit.
__global__ __launch_bounds__(256, 3) void scores_gemm_kernel(
    const unsigned short* __restrict__ encB, const unsigned short* __restrict__ WeTcB,
    const float* __restrict__ Wo, const float* __restrict__ dp,
    float* __restrict__ parts) {
    __shared__ unsigned short sA[BM * BK];  // 16 KB
    __shared__ unsigned short sB[BN * BK];  // 16 KB
    __shared__ float sRed[2][BM];

    int tid = threadIdx.x;
    int w = tid >> 6, l = tid & 63;
    int l16 = l & 15, quad = l >> 4;
    int wm = w & 1, wn = w >> 1;
    int bid = blockIdx.x;
    int xcd = bid & 7;
    int sq = bid >> 3;
    int nt = sq & 3;                          // sibling index (same XCD for all 4)
    size_t mt = (size_t)((sq >> 2) << 3) + xcd;  // [0,512)
    size_t m0 = mt * BM;
    int n0 = nt * BN;
    int b = (int)(m0 >> 12);

    // staging lane constants
    int lrow = l >> 3, lcp = l & 7;
    int qa = lcp ^ (lrow & 7);  // logical k-block gathered by this lane
    const unsigned short* gA = encB + (m0 + w * 8 + lrow) * E_ + qa * 8;
    const unsigned short* gB = WeTcB + (size_t)n0 * BK + (w * 8) * BK + l * 8;
    unsigned short* sAb = sA + (w * 8) * BK;
    unsigned short* sBb = sB + (w * 8) * BK;

    f32x4 acc[4][4];
#pragma unroll
    for (int i = 0; i < 4; ++i)
#pragma unroll
        for (int j = 0; j < 4; ++j) acc[i][j] = (f32x4)0.f;

    int arow = (wm * 64 + l16) * BK;
    int brow = (wn * 64 + l16) * BK;
    int sw = l16 & 7;

    for (int c = 0; c < NCHUNK; ++c) {
        __syncthreads();  // prior chunk's frag reads complete
        int k0 = c * BK;
#pragma unroll
        for (int i = 0; i < 4; ++i) {
            gld16(gA + (size_t)i * 32 * E_ + k0, sAb + i * 32 * BK);
            gld16(gB + (size_t)c * (H_ * BK) + i * 32 * BK, sBb + i * 32 * BK);
        }
        __syncthreads();  // copies landed (compiler drains vmcnt before barrier)
#pragma unroll
        for (int half = 0; half < 2; ++half) {
            int koff = (((half * 4 + quad) ^ sw) << 3);
            bf16x8 aR[4], bR[4];
#pragma unroll
            for (int i = 0; i < 4; ++i)
                aR[i] = *(const bf16x8*)(sA + arow + i * 16 * BK + koff);
#pragma unroll
            for (int j = 0; j < 4; ++j)
                bR[j] = *(const bf16x8*)(sB + brow + j * 16 * BK + koff);
#pragma unroll
            for (int i = 0; i < 4; ++i)
#pragma unroll
                for (int j = 0; j < 4; ++j)
                    acc[i][j] = __builtin_amdgcn_mfma_f32_16x16x32_bf16(aR[i], bR[j], acc[i][j], 0, 0, 0);
        }
    }

    // Epilogue: tanh(acc + dp) * Wo, partial reduce over this block's 128 h.
    float dpv[4], wov[4];
    const float* dpb = dp + b * H_;
#pragma unroll
    for (int j = 0; j < 4; ++j) {
        int h = n0 + wn * 64 + j * 16 + l16;
        dpv[j] = dpb[h];
        wov[j] = Wo[h];
    }
#pragma unroll
    for (int i = 0; i < 4; ++i)
#pragma unroll
        for (int r = 0; r < 4; ++r) {
            float s = 0.f;
#pragma unroll
            for (int j = 0; j < 4; ++j) {
                float x = acc[i][j][r] + dpv[j];
                float e = __expf(2.f * x);
                s += (1.f - 2.f / (e + 1.f)) * wov[j];
            }
            s += __shfl_xor(s, 1, 64);
            s += __shfl_xor(s, 2, 64);
            s += __shfl_xor(s, 4, 64);
            s += __shfl_xor(s, 8, 64);
            if (l16 == 0) sRed[wn][wm * 64 + i * 16 + quad * 4 + r] = s;
        }
    __syncthreads();
    if (tid < BM) {
        int s_in = (int)(m0 & (S_ - 1)) + tid;
        parts[(size_t)(nt * B_ + b) * S_ + s_in] = sRed[0][tid] + sRed[1][tid];
    }
}

// Row softmax stats only: stats[b] = (max, sumexp) over summed 4-slab scores.
// Softmax itself is folded into the ctx pass (exp in partial, 1/Z in reduce).
__global__ __launch_bounds__(256) void stats_kernel(const float* __restrict__ parts,
                                                    float2* __restrict__ stats) {
    int b = blockIdx.x, tid = threadIdx.x;
    const float4* p0 = (const float4*)(parts + (size_t)(0 * B_ + b) * S_);
    const float4* p1 = (const float4*)(parts + (size_t)(1 * B_ + b) * S_);
    const float4* p2 = (const float4*)(parts + (size_t)(2 * B_ + b) * S_);
    const float4* p3 = (const float4*)(parts + (size_t)(3 * B_ + b) * S_);
    float4 v[4];
    float m = -1e30f;
#pragma unroll
    for (int i = 0; i < 4; ++i) {
        int idx = i * 256 + tid;
        float4 a0 = p0[idx], a1 = p1[idx], a2 = p2[idx], a3 = p3[idx];
        v[i].x = a0.x + a1.x + a2.x + a3.x;
        v[i].y = a0.y + a1.y + a2.y + a3.y;
        v[i].z = a0.z + a1.z + a2.z + a3.z;
        v[i].w = a0.w + a1.w + a2.w + a3.w;
        m = fmaxf(m, fmaxf(fmaxf(v[i].x, v[i].y), fmaxf(v[i].z, v[i].w)));
    }
    for (int off = 32; off; off >>= 1) m = fmaxf(m, __shfl_xor(m, off, 64));
    __shared__ float redm[4];
    __shared__ float reds[4];
    if ((tid & 63) == 0) redm[tid >> 6] = m;
    __syncthreads();
    m = fmaxf(fmaxf(redm[0], redm[1]), fmaxf(redm[2], redm[3]));
    float s = 0.f;
#pragma unroll
    for (int i = 0; i < 4; ++i) {
        s += __expf(v[i].x - m) + __expf(v[i].y - m);
        s += __expf(v[i].z - m) + __expf(v[i].w - m);
    }
    for (int off = 32; off; off >>= 1) s += __shfl_xor(s, off, 64);
    if ((tid & 63) == 0) reds[tid >> 6] = s;
    __syncthreads();
    if (tid == 0) {
        stats[b] = make_float2(m, reds[0] + reds[1] + reds[2] + reds[3]);
    }
}

// ctx partials from bf16 enc copy, unnormalized weights exp(sc - m).
// Block = (b, 128-s chunk); thread: 8 e-cols, 64 s-rows. 64 partial slabs per b.
__global__ __launch_bounds__(256) void ctx_partial_bf16(
    const unsigned short* __restrict__ encB, const float* __restrict__ parts,
    const float2* __restrict__ stats, float* __restrict__ part) {
    int b = blockIdx.x >> 5;
    int c = blockIdx.x & 31;
    int s0 = c * 128;
    int tid = threadIdx.x;
    __shared__ float w[128];
    if (tid < 128) {
        size_t idx = (size_t)b * S_ + s0 + tid;
        float x = parts[(size_t)(0 * B_) * S_ + idx] + parts[(size_t)(1 * B_) * S_ + idx] +
                  parts[(size_t)(2 * B_) * S_ + idx] + parts[(size_t)(3 * B_) * S_ + idx];
        w[tid] = __expf(x - stats[b].x);
    }
    __syncthreads();
    int e8 = (tid & 127) * 8;
    int sh = tid >> 7;
    const unsigned short* base = encB + ((size_t)b * S_ + s0 + sh * 64) * E_ + e8;
    const float* wp = w + sh * 64;
    float acc[8];
#pragma unroll
    for (int t = 0; t < 8; ++t) acc[t] = 0.f;
    for (int s = 0; s < 64; s += 8) {
        u16x8 v[8];
#pragma unroll
        for (int u = 0; u < 8; ++u) v[u] = *(const u16x8*)(base + (size_t)(s + u) * E_);
#pragma unroll
        for (int u = 0; u < 8; ++u) {
            float ws = wp[s + u];
#pragma unroll
            for (int t = 0; t < 8; ++t) acc[t] = fmaf(ws, bf2f(v[u][t]), acc[t]);
        }
    }
    float* po = part + ((size_t)(b * 64 + c * 2 + sh)) * E_ + e8;
    *(float4*)(po) = make_float4(acc[0], acc[1], acc[2], acc[3]);
    *(float4*)(po + 4) = make_float4(acc[4], acc[5], acc[6], acc[7]);
}

__global__ __launch_bounds__(256) void ctx_reduce(const float* __restrict__ part,
                                                  const float2* __restrict__ stats,
                                                  float* __restrict__ out) {
    int idx = blockIdx.x * 256 + threadIdx.x;  // 16*1024
    int b = idx >> 10;
    int e = idx & 1023;
    const float* p = part + (size_t)b * 64 * E_ + e;
    float s0 = 0.f, s1 = 0.f, s2 = 0.f, s3 = 0.f;
    for (int c = 0; c < 64; c += 4) {
        s0 += p[(size_t)(c + 0) * E_];
        s1 += p[(size_t)(c + 1) * E_];
        s2 += p[(size_t)(c + 2) * E_];
        s3 += p[(size_t)(c + 3) * E_];
    }
    out[idx] = ((s0 + s1) + (s2 + s3)) * (1.f / stats[b].y);
}

extern "C" void kernel_launch(void* const* d_in, const int* in_sizes, int n_in,
                              void* d_out, int out_size, void* d_ws, size_t ws_size,
                              hipStream_t stream) {
    const float* enc = (const float*)d_in[0];  // [16,4096,1024]
    const float* dec = (const float*)d_in[1];  // [16,1024]
    const float* We  = (const float*)d_in[2];  // [1024,512]
    const float* be  = (const float*)d_in[3];  // [512]
    const float* Wd  = (const float*)d_in[4];  // [1024,512]
    const float* bd  = (const float*)d_in[5];  // [512]
    const float* Wo  = (const float*)d_in[6];  // [512,1]
    float* out = (float*)d_out;                // [16,1024]

    char* wsp = (char*)d_ws;
    unsigned short* WeTcB = (unsigned short*)wsp;              // 1 MiB
    float* dp = (float*)(wsp + (1 << 20));                     // 32 KiB
    float2* stats = (float2*)(wsp + (1 << 20) + (32 << 10));   // 128 B
    float* parts = (float*)(wsp + (1 << 20) + (64 << 10));     // 1 MiB (4 slabs)
    float* part = (float*)(wsp + (4 << 20));                   // 4 MiB
    unsigned short* encB = (unsigned short*)(wsp + (8 << 20)); // 128 MiB

    prep_conv_kernel<<<192 + 16384, 256, 0, stream>>>(enc, We, dec, Wd, bd, be,
                                                      WeTcB, dp, encB);
    scores_gemm_kernel<<<(B_ * S_ / BM) * (H_ / BN), 256, 0, stream>>>(
        encB, WeTcB, Wo, dp, parts);
    stats_kernel<<<B_, 256, 0, stream>>>(parts, stats);
    ctx_partial_bf16<<<B_ * 32, 256, 0, stream>>>(encB, parts, stats, part);
    ctx_reduce<<<B_ * E_ / 256, 256, 0, stream>>>(part, stats, out);
}